// Round 7
// baseline (355.709 us; speedup 1.0000x reference)
//
#include <hip/hip_runtime.h>
#include <math.h>

#define B_  16
#define N_  8192
#define D_  128
#define H_  64
#define E_  64
#define EPSLN 1e-5f

typedef __attribute__((ext_vector_type(8))) short short8;
typedef __attribute__((ext_vector_type(4))) short short4v;
typedef __attribute__((ext_vector_type(4))) float f32x4;

// workspace layout (bytes):
//   partial : B*128*D floats @ 0        (1048576)  per-block colacc partials
//   Mt      : B*E*D bf16     @ 1048576  (262144)   Mt[b][e][d]
//   Tg      : B*E floats     @ 1310720  (4096)
//   Cg      : B*E floats     @ 1314816  (4096)
//   murs    : B*N float2     @ 1318912  (1048576)  per-row {mu, rs}
//   cnt     : B uints        @ 2367488  (64)       last-block tickets (memset/launch)
#define WSB_PART 0
#define WSB_MT   1048576
#define WSB_T    1310720
#define WSB_C    1314816
#define WSB_MURS 1318912
#define WSB_CNT  2367488

static __device__ __forceinline__ unsigned short f2bf(float f) {
    union { float f; unsigned u; } c; c.f = f;
    unsigned u = c.u;
    return (unsigned short)((u + 0x7FFFu + ((u >> 16) & 1u)) >> 16);  // RNE
}

// ---------------------------------------------------------------------------
// Kernel A: verified round-6 body (coalesced 64-row tile -> stats -> weighted
// colsum -> partial + {mu,rs} dump), plus the round-4-verified last-block
// ticket: the last of each batch's 128 blocks runs the (verified) combine ->
// Mt (bf16 [e][d]), Tg, Cg. Combine LDS (P etc.) aliases the dead xs tile.
// ---------------------------------------------------------------------------
__global__ __launch_bounds__(256, 4) void k_stats(
    const float* __restrict__ x,
    const float* __restrict__ ln_w, const float* __restrict__ ln_b,
    const float* __restrict__ Wl,   const float* __restrict__ bl,
    const float* __restrict__ Wr,   const float* __restrict__ br,
    const float* __restrict__ Wo,   const float* __restrict__ bo,
    float* __restrict__ partial, float2* __restrict__ murs,
    unsigned* __restrict__ cnt,
    unsigned short* __restrict__ Mt,
    float* __restrict__ Tg, float* __restrict__ Cg)
{
    __shared__ float smem[64 * 132 + 64 + 64 + 128];   // xs | mul | rsl | red
    __shared__ int   isLast;
    float* xs  = smem;               // 8448 floats (row stride 132)
    float* mul = smem + 8448;        // 64
    float* rsl = smem + 8512;        // 64
    float* red = smem + 8576;        // 128

    int b = blockIdx.y, t = threadIdx.x;
    int rowbase = blockIdx.x * 64;
    size_t gbase = (size_t)(b * N_ + rowbase) * 32;  // float4 units

    // stage: 2048 float4s, coalesced
    const float4* x4 = (const float4*)x;
#pragma unroll
    for (int k = 0; k < 8; ++k) {
        int idx = t + 256 * k;
        int row = idx >> 5, c4 = idx & 31;
        *(float4*)&xs[row * 132 + c4 * 4] = x4[gbase + idx];
    }
    __syncthreads();

    // stats: 4 threads per row
    {
        int r = t >> 2, q = t & 3;
        float s = 0.f, s2 = 0.f;
#pragma unroll
        for (int i = 0; i < 8; ++i) {
            float4 v = *(const float4*)&xs[r * 132 + q * 32 + i * 4];
            s  += (v.x + v.y) + (v.z + v.w);
            s2 += (v.x * v.x + v.y * v.y) + (v.z * v.z + v.w * v.w);
        }
        s  += __shfl_xor(s, 1, 64);  s  += __shfl_xor(s, 2, 64);
        s2 += __shfl_xor(s2, 1, 64); s2 += __shfl_xor(s2, 2, 64);
        if (q == 0) {
            float mu  = s * (1.f / D_);
            float var = s2 * (1.f / D_) - mu * mu;
            mul[r] = mu;
            rsl[r] = rsqrtf(var + EPSLN);
        }
    }
    __syncthreads();

    if (t < 64) {
        float2 mr; mr.x = mul[t]; mr.y = rsl[t];
        murs[(size_t)b * N_ + rowbase + t] = mr;
    }

    // weighted colsum: col c, half hh (rows hh*32..+31); 2-way banks = free
    {
        int c = t & 127, hh = t >> 7;
        float acc = 0.f;
#pragma unroll 8
        for (int i = 0; i < 32; ++i) {
            int r = hh * 32 + i;
            acc += rsl[r] * (xs[r * 132 + c] - mul[r]);
        }
        if (hh == 1) red[c] = acc;
        __syncthreads();
        if (hh == 0)
            partial[((size_t)b * 128 + blockIdx.x) * D_ + c] = acc + red[c];
    }

    // ---- last-block ticket (round-4-verified pattern) ----------------------
    __threadfence();                         // release partial
    __syncthreads();
    if (t == 0) isLast = (atomicAdd(&cnt[b], 1u) == 127u);
    __syncthreads();
    if (!isLast) return;
    __threadfence();                         // acquire other blocks' partials
    __syncthreads();                         // xs reads done; safe to alias

    // ---- combine (verified round-6 algebra, all 4 dblk in this block) ------
    float* P    = smem;                      // 4096 floats (aliases xs)
    float* cm   = smem + 4096;               // 128
    float* ml   = smem + 4224;               // 64
    float* uu   = smem + 4288;               // 64
    float* qq   = smem + 4352;               // 64
    float* red2 = smem + 4416;               // 256

    {   // colacc[b,d] = sum over 128 block partials (2 threads per d)
        int d = t & 127, hhf = t >> 7;
        float sacc = 0.f;
        for (int j = hhf * 64; j < hhf * 64 + 64; ++j)
            sacc += partial[((size_t)b * 128 + j) * D_ + d];
        red2[t] = sacc;
    }
    __syncthreads();
    if (t < D_) cm[t] = ln_w[t] * (red2[t] + red2[t + 128]) * (1.f / N_) + ln_b[t];
    __syncthreads();

    if (t < H_) {
        float a = bl[t], u = 0.f, q = 0.f;
        for (int d = 0; d < D_; ++d) {
            float wr = Wr[d * H_ + t];
            a += cm[d] * Wl[d * H_ + t];
            u += ln_w[d] * wr;
            q += ln_b[d] * wr;
        }
        ml[t] = a; uu[t] = u; qq[t] = q + br[t];
    }
    __syncthreads();

#pragma unroll
    for (int k = 0; k < 16; ++k) {
        int idx = t + 256 * k;
        P[idx] = ml[idx >> 6] * Wo[idx];
    }
    __syncthreads();

    for (int dblk = 0; dblk < 4; ++dblk) {
        int d  = dblk * 32 + (t >> 3);
        int eo = (t & 7) * 8;
        float a0 = 0, a1 = 0, a2 = 0, a3 = 0, a4 = 0, a5 = 0, a6 = 0, a7 = 0;
        for (int h = 0; h < H_; ++h) {
            float wr = Wr[d * H_ + h];
            const float4* p4 = (const float4*)&P[h * E_ + eo];
            float4 pa = p4[0], pb = p4[1];
            a0 += wr * pa.x; a1 += wr * pa.y; a2 += wr * pa.z; a3 += wr * pa.w;
            a4 += wr * pb.x; a5 += wr * pb.y; a6 += wr * pb.z; a7 += wr * pb.w;
        }
        float wd = ln_w[d];
        size_t mb = (size_t)b * E_ * D_;
        Mt[mb + (size_t)(eo + 0) * D_ + d] = f2bf(wd * a0);
        Mt[mb + (size_t)(eo + 1) * D_ + d] = f2bf(wd * a1);
        Mt[mb + (size_t)(eo + 2) * D_ + d] = f2bf(wd * a2);
        Mt[mb + (size_t)(eo + 3) * D_ + d] = f2bf(wd * a3);
        Mt[mb + (size_t)(eo + 4) * D_ + d] = f2bf(wd * a4);
        Mt[mb + (size_t)(eo + 5) * D_ + d] = f2bf(wd * a5);
        Mt[mb + (size_t)(eo + 6) * D_ + d] = f2bf(wd * a6);
        Mt[mb + (size_t)(eo + 7) * D_ + d] = f2bf(wd * a7);
    }

    if (t < E_) {
        float T = 0.f, C = bo[t];
        for (int h = 0; h < H_; ++h) {
            float p = P[h * E_ + t];
            T += uu[h] * p;
            C += qq[h] * p;
        }
        Tg[b * E_ + t] = T;
        Cg[b * E_ + t] = C;
    }
}

// ---------------------------------------------------------------------------
// Kernel C: verified round-6 body at 512 threads (8 waves/block, 2 blocks/CU
// -> 4 waves/SIMD: double the latency hiding during staging). Same 256-row
// tile, same XOR-swizzled LDS layout; each wave owns 32 rows (2 m-tiles).
// ---------------------------------------------------------------------------
__global__ __launch_bounds__(512, 4) void k_gemm4(const float* __restrict__ x,
                                                  const float2* __restrict__ murs,
                                                  const unsigned short* __restrict__ Mt,
                                                  const float* __restrict__ Tg,
                                                  const float* __restrict__ Cg,
                                                  float* __restrict__ out) {
    __shared__ short xs[256 * 128];          // 64 KB bf16, swizzled granules
    __shared__ float muL[256], rsL[256], Tl[E_], Cl[E_];

    int b = blockIdx.y, bx = blockIdx.x, t = threadIdx.x;
    int rowbase = bx * 256;

    if (t < E_) { Tl[t] = Tg[b * E_ + t]; Cl[t] = Cg[b * E_ + t]; }
    if (t < 256) {
        float2 mr = murs[(size_t)b * N_ + rowbase + t];
        muL[t] = mr.x; rsL[t] = mr.y;
    }

    const float4* x4 = (const float4*)x;
    size_t gbase = (size_t)(b * N_ + rowbase) * 32;  // float4 units

#pragma unroll
    for (int k = 0; k < 16; ++k) {
        int idx = t + 512 * k;
        int row = idx >> 5, c4 = idx & 31;
        float4 v = x4[gbase + idx];                   // coalesced
        short4v sv;
        sv[0] = (short)f2bf(v.x); sv[1] = (short)f2bf(v.y);
        sv[2] = (short)f2bf(v.z); sv[3] = (short)f2bf(v.w);
        int g2 = c4 >> 1, half = c4 & 1;
        *(short4v*)&xs[row * 128 + ((g2 ^ (row & 15)) << 3) + (half << 2)] = sv;
    }
    __syncthreads();

    // ---- verified MFMA main + epilogue (2 m-tiles per wave) ----
    int wv = t >> 6, lane = t & 63;
    int m16 = lane & 15, quad = lane >> 4;

    f32x4 acc[2][4];
#pragma unroll
    for (int i = 0; i < 2; ++i)
#pragma unroll
        for (int j = 0; j < 4; ++j) acc[i][j] = (f32x4){0.f, 0.f, 0.f, 0.f};

    const unsigned short* Mb = Mt + (size_t)b * E_ * D_;

#pragma unroll
    for (int kc = 0; kc < 4; ++kc) {
        short8 af[2], bf[4];
#pragma unroll
        for (int mt = 0; mt < 2; ++mt) {
            int row = wv * 32 + mt * 16 + m16;
            int g = kc * 4 + quad;
            af[mt] = *(const short8*)&xs[row * 128 + ((g ^ m16) * 8)];
        }
#pragma unroll
        for (int nt = 0; nt < 4; ++nt) {
            bf[nt] = *(const short8*)(Mb + (size_t)(nt * 16 + m16) * D_ + kc * 32 + quad * 8);
        }
#pragma unroll
        for (int mt = 0; mt < 2; ++mt)
#pragma unroll
            for (int nt = 0; nt < 4; ++nt)
                acc[mt][nt] = __builtin_amdgcn_mfma_f32_16x16x32_bf16(
                    af[mt], bf[nt], acc[mt][nt], 0, 0, 0);
    }

    size_t outbase = (size_t)(b * N_ + rowbase) * E_;
#pragma unroll
    for (int mt = 0; mt < 2; ++mt) {
        int rb = wv * 32 + mt * 16 + quad * 4;
        float mu0 = muL[rb + 0], rs0 = rsL[rb + 0];
        float mu1 = muL[rb + 1], rs1 = rsL[rb + 1];
        float mu2 = muL[rb + 2], rs2 = rsL[rb + 2];
        float mu3 = muL[rb + 3], rs3 = rsL[rb + 3];
#pragma unroll
        for (int nt = 0; nt < 4; ++nt) {
            int col = nt * 16 + m16;
            float Tc = Tl[col], Cc = Cl[col];
            float* o = out + outbase + (size_t)rb * E_ + col;
            o[0 * E_] = rs0 * (acc[mt][nt][0] - mu0 * Tc) + Cc;
            o[1 * E_] = rs1 * (acc[mt][nt][1] - mu1 * Tc) + Cc;
            o[2 * E_] = rs2 * (acc[mt][nt][2] - mu2 * Tc) + Cc;
            o[3 * E_] = rs3 * (acc[mt][nt][3] - mu3 * Tc) + Cc;
        }
    }
}

extern "C" void kernel_launch(void* const* d_in, const int* in_sizes, int n_in,
                              void* d_out, int out_size, void* d_ws, size_t ws_size,
                              hipStream_t stream) {
    const float* x    = (const float*)d_in[0];
    const float* ln_w = (const float*)d_in[1];
    const float* ln_b = (const float*)d_in[2];
    const float* Wl   = (const float*)d_in[3];
    const float* bl   = (const float*)d_in[4];
    const float* Wr   = (const float*)d_in[5];
    const float* br   = (const float*)d_in[6];
    const float* Wo   = (const float*)d_in[7];
    const float* bo   = (const float*)d_in[8];
    float* out = (float*)d_out;
    char* ws   = (char*)d_ws;

    float*          partial = (float*)(ws + WSB_PART);
    unsigned short* Mt      = (unsigned short*)(ws + WSB_MT);
    float*          Tg      = (float*)(ws + WSB_T);
    float*          Cg      = (float*)(ws + WSB_C);
    float2*         murs    = (float2*)(ws + WSB_MURS);
    unsigned*       cnt     = (unsigned*)(ws + WSB_CNT);

    hipMemsetAsync(cnt, 0, B_ * sizeof(unsigned), stream);

    k_stats<<<dim3(128, 16), dim3(256), 0, stream>>>(
        x, ln_w, ln_b, Wl, bl, Wr, br, Wo, bo,
        partial, murs, cnt, Mt, Tg, Cg);

    k_gemm4<<<dim3(32, 16), dim3(512), 0, stream>>>(x, murs, Mt, Tg, Cg, out);
}

// Round 8
// 155.058 us; speedup vs baseline: 2.2940x; 2.2940x over previous
//
#include <hip/hip_runtime.h>
#include <math.h>

#define B_  16
#define N_  8192
#define D_  128
#define H_  64
#define E_  64
#define EPSLN 1e-5f

typedef __attribute__((ext_vector_type(8))) short short8;
typedef __attribute__((ext_vector_type(4))) short short4v;
typedef __attribute__((ext_vector_type(4))) float f32x4;

// workspace layout (bytes):
//   partial : B*128*D floats @ 0        (1048576)  per-block colacc partials
//   Mt      : B*E*D bf16     @ 1048576  (262144)   Mt[b][e][d]
//   Tg      : B*E floats     @ 1310720  (4096)
//   Cg      : B*E floats     @ 1314816  (4096)
//   murs    : B*N float2     @ 1318912  (1048576)  per-row {mu, rs}
#define WSB_PART 0
#define WSB_MT   1048576
#define WSB_T    1310720
#define WSB_C    1314816
#define WSB_MURS 1318912

static __device__ __forceinline__ unsigned short f2bf(float f) {
    union { float f; unsigned u; } c; c.f = f;
    unsigned u = c.u;
    return (unsigned short)((u + 0x7FFFu + ((u >> 16) & 1u)) >> 16);  // RNE
}

// ---------------------------------------------------------------------------
// Kernel A (verified round-6, NO fences/atomics): coalesced 64-row tile ->
// stats -> weighted colsum -> per-block partial + {mu,rs} dump.
// ---------------------------------------------------------------------------
__global__ __launch_bounds__(256) void k_stats(const float* __restrict__ x,
                                               float* __restrict__ partial,
                                               float2* __restrict__ murs) {
    __shared__ float xs[64 * 132];           // 33.8 KB, row stride 132
    __shared__ float mul[64], rsl[64], red[128];
    int b = blockIdx.y, t = threadIdx.x;
    int rowbase = blockIdx.x * 64;
    size_t gbase = (size_t)(b * N_ + rowbase) * 32;  // float4 units

    // stage: 2048 float4s, coalesced
    const float4* x4 = (const float4*)x;
#pragma unroll
    for (int k = 0; k < 8; ++k) {
        int idx = t + 256 * k;
        int row = idx >> 5, c4 = idx & 31;
        *(float4*)&xs[row * 132 + c4 * 4] = x4[gbase + idx];
    }
    __syncthreads();

    // stats: 4 threads per row
    {
        int r = t >> 2, q = t & 3;
        float s = 0.f, s2 = 0.f;
#pragma unroll
        for (int i = 0; i < 8; ++i) {
            float4 v = *(const float4*)&xs[r * 132 + q * 32 + i * 4];
            s  += (v.x + v.y) + (v.z + v.w);
            s2 += (v.x * v.x + v.y * v.y) + (v.z * v.z + v.w * v.w);
        }
        s  += __shfl_xor(s, 1, 64);  s  += __shfl_xor(s, 2, 64);
        s2 += __shfl_xor(s2, 1, 64); s2 += __shfl_xor(s2, 2, 64);
        if (q == 0) {
            float mu  = s * (1.f / D_);
            float var = s2 * (1.f / D_) - mu * mu;
            mul[r] = mu;
            rsl[r] = rsqrtf(var + EPSLN);
        }
    }
    __syncthreads();

    if (t < 64) {
        float2 mr; mr.x = mul[t]; mr.y = rsl[t];
        murs[(size_t)b * N_ + rowbase + t] = mr;
    }

    // weighted colsum: col c, half hh (rows hh*32..+31); 2-way banks = free
    int c = t & 127, hh = t >> 7;
    float acc = 0.f;
#pragma unroll 8
    for (int i = 0; i < 32; ++i) {
        int r = hh * 32 + i;
        acc += rsl[r] * (xs[r * 132 + c] - mul[r]);
    }
    if (hh == 1) red[c] = acc;
    __syncthreads();
    if (hh == 0)
        partial[((size_t)b * 128 + blockIdx.x) * D_ + c] = acc + red[c];
}

// ---------------------------------------------------------------------------
// Kernel B (verified round-6): tiny per-batch combine; emits Mt (bf16 [e][d]),
// T, C. cm from 2-level partial reduction.
// ---------------------------------------------------------------------------
__global__ __launch_bounds__(256) void k_combine(const float* __restrict__ partial,
                                                 const float* __restrict__ ln_w,
                                                 const float* __restrict__ ln_b,
                                                 const float* __restrict__ Wl,
                                                 const float* __restrict__ bl,
                                                 const float* __restrict__ Wr,
                                                 const float* __restrict__ br,
                                                 const float* __restrict__ Wo,
                                                 const float* __restrict__ bo,
                                                 unsigned short* __restrict__ Mt,
                                                 float* __restrict__ Tg,
                                                 float* __restrict__ Cg) {
    int b = blockIdx.y, dblk = blockIdx.x, t = threadIdx.x;
    __shared__ float cm[D_], ml[H_], uu[H_], qq[H_];
    __shared__ float P[H_ * E_];
    __shared__ float red2[256];

    {   // colacc[b,d] = sum over 128 block partials (2 threads per d)
        int d = t & 127, hhf = t >> 7;
        float sacc = 0.f;
        for (int j = hhf * 64; j < hhf * 64 + 64; ++j)
            sacc += partial[((size_t)b * 128 + j) * D_ + d];
        red2[t] = sacc;
    }
    __syncthreads();
    if (t < D_) cm[t] = ln_w[t] * (red2[t] + red2[t + 128]) * (1.f / N_) + ln_b[t];
    __syncthreads();

    if (t < H_) {
        float a = bl[t], u = 0.f, q = 0.f;
        for (int d = 0; d < D_; ++d) {
            float wr = Wr[d * H_ + t];
            a += cm[d] * Wl[d * H_ + t];
            u += ln_w[d] * wr;
            q += ln_b[d] * wr;
        }
        ml[t] = a; uu[t] = u; qq[t] = q + br[t];
    }
    __syncthreads();

#pragma unroll
    for (int k = 0; k < 16; ++k) {
        int idx = t + 256 * k;
        P[idx] = ml[idx >> 6] * Wo[idx];
    }
    __syncthreads();

    int d  = dblk * 32 + (t >> 3);
    int eo = (t & 7) * 8;
    float a0 = 0, a1 = 0, a2 = 0, a3 = 0, a4 = 0, a5 = 0, a6 = 0, a7 = 0;
    for (int h = 0; h < H_; ++h) {
        float wr = Wr[d * H_ + h];
        const float4* p4 = (const float4*)&P[h * E_ + eo];
        float4 pa = p4[0], pb = p4[1];
        a0 += wr * pa.x; a1 += wr * pa.y; a2 += wr * pa.z; a3 += wr * pa.w;
        a4 += wr * pb.x; a5 += wr * pb.y; a6 += wr * pb.z; a7 += wr * pb.w;
    }
    float wd = ln_w[d];
    size_t mb = (size_t)b * E_ * D_;
    Mt[mb + (size_t)(eo + 0) * D_ + d] = f2bf(wd * a0);
    Mt[mb + (size_t)(eo + 1) * D_ + d] = f2bf(wd * a1);
    Mt[mb + (size_t)(eo + 2) * D_ + d] = f2bf(wd * a2);
    Mt[mb + (size_t)(eo + 3) * D_ + d] = f2bf(wd * a3);
    Mt[mb + (size_t)(eo + 4) * D_ + d] = f2bf(wd * a4);
    Mt[mb + (size_t)(eo + 5) * D_ + d] = f2bf(wd * a5);
    Mt[mb + (size_t)(eo + 6) * D_ + d] = f2bf(wd * a6);
    Mt[mb + (size_t)(eo + 7) * D_ + d] = f2bf(wd * a7);

    if (dblk == 0 && t < E_) {
        float T = 0.f, C = bo[t];
        for (int h = 0; h < H_; ++h) {
            float p = P[h * E_ + t];
            T += uu[h] * p;
            C += qq[h] * p;
        }
        Tg[b * E_ + t] = T;
        Cg[b * E_ + t] = C;
    }
}

// ---------------------------------------------------------------------------
// Kernel C: verified round-6 staging/MFMA at HALF tile (128 rows, 32 KB LDS)
// -> 4 blocks/CU = 4 waves/SIMD during staging (2x latency hiding), 1024
// blocks. Each wave: rows wv*32..+31 (2 m-tiles), cols 0..63 (4 n-tiles).
// Swizzle algebra identical (row&15 invariant).
// ---------------------------------------------------------------------------
__global__ __launch_bounds__(256, 4) void k_gemm5(const float* __restrict__ x,
                                                  const float2* __restrict__ murs,
                                                  const unsigned short* __restrict__ Mt,
                                                  const float* __restrict__ Tg,
                                                  const float* __restrict__ Cg,
                                                  float* __restrict__ out) {
    __shared__ short xs[128 * 128];          // 32 KB bf16, swizzled granules
    __shared__ float muL[128], rsL[128], Tl[E_], Cl[E_];

    int b = blockIdx.y, bx = blockIdx.x, t = threadIdx.x;
    int rowbase = bx * 128;

    if (t < E_) { Tl[t] = Tg[b * E_ + t]; Cl[t] = Cg[b * E_ + t]; }
    if (t < 128) {
        float2 mr = murs[(size_t)b * N_ + rowbase + t];
        muL[t] = mr.x; rsL[t] = mr.y;
    }

    const float4* x4 = (const float4*)x;
    size_t gbase = (size_t)(b * N_ + rowbase) * 32;  // float4 units

#pragma unroll
    for (int k = 0; k < 16; ++k) {
        int idx = t + 256 * k;
        int row = idx >> 5, c4 = idx & 31;
        float4 v = x4[gbase + idx];                   // coalesced
        short4v sv;
        sv[0] = (short)f2bf(v.x); sv[1] = (short)f2bf(v.y);
        sv[2] = (short)f2bf(v.z); sv[3] = (short)f2bf(v.w);
        int g2 = c4 >> 1, half = c4 & 1;
        *(short4v*)&xs[row * 128 + ((g2 ^ (row & 15)) << 3) + (half << 2)] = sv;
    }
    __syncthreads();

    // ---- verified MFMA main + epilogue (2 m-tiles per wave) ----
    int wv = t >> 6, lane = t & 63;
    int m16 = lane & 15, quad = lane >> 4;

    f32x4 acc[2][4];
#pragma unroll
    for (int i = 0; i < 2; ++i)
#pragma unroll
        for (int j = 0; j < 4; ++j) acc[i][j] = (f32x4){0.f, 0.f, 0.f, 0.f};

    const unsigned short* Mb = Mt + (size_t)b * E_ * D_;

#pragma unroll
    for (int kc = 0; kc < 4; ++kc) {
        short8 af[2], bf[4];
#pragma unroll
        for (int mt = 0; mt < 2; ++mt) {
            int row = wv * 32 + mt * 16 + m16;
            int g = kc * 4 + quad;
            af[mt] = *(const short8*)&xs[row * 128 + ((g ^ m16) * 8)];
        }
#pragma unroll
        for (int nt = 0; nt < 4; ++nt) {
            bf[nt] = *(const short8*)(Mb + (size_t)(nt * 16 + m16) * D_ + kc * 32 + quad * 8);
        }
#pragma unroll
        for (int mt = 0; mt < 2; ++mt)
#pragma unroll
            for (int nt = 0; nt < 4; ++nt)
                acc[mt][nt] = __builtin_amdgcn_mfma_f32_16x16x32_bf16(
                    af[mt], bf[nt], acc[mt][nt], 0, 0, 0);
    }

    size_t outbase = (size_t)(b * N_ + rowbase) * E_;
#pragma unroll
    for (int mt = 0; mt < 2; ++mt) {
        int rb = wv * 32 + mt * 16 + quad * 4;
        float mu0 = muL[rb + 0], rs0 = rsL[rb + 0];
        float mu1 = muL[rb + 1], rs1 = rsL[rb + 1];
        float mu2 = muL[rb + 2], rs2 = rsL[rb + 2];
        float mu3 = muL[rb + 3], rs3 = rsL[rb + 3];
#pragma unroll
        for (int nt = 0; nt < 4; ++nt) {
            int col = nt * 16 + m16;
            float Tc = Tl[col], Cc = Cl[col];
            float* o = out + outbase + (size_t)rb * E_ + col;
            o[0 * E_] = rs0 * (acc[mt][nt][0] - mu0 * Tc) + Cc;
            o[1 * E_] = rs1 * (acc[mt][nt][1] - mu1 * Tc) + Cc;
            o[2 * E_] = rs2 * (acc[mt][nt][2] - mu2 * Tc) + Cc;
            o[3 * E_] = rs3 * (acc[mt][nt][3] - mu3 * Tc) + Cc;
        }
    }
}

extern "C" void kernel_launch(void* const* d_in, const int* in_sizes, int n_in,
                              void* d_out, int out_size, void* d_ws, size_t ws_size,
                              hipStream_t stream) {
    const float* x    = (const float*)d_in[0];
    const float* ln_w = (const float*)d_in[1];
    const float* ln_b = (const float*)d_in[2];
    const float* Wl   = (const float*)d_in[3];
    const float* bl   = (const float*)d_in[4];
    const float* Wr   = (const float*)d_in[5];
    const float* br   = (const float*)d_in[6];
    const float* Wo   = (const float*)d_in[7];
    const float* bo   = (const float*)d_in[8];
    float* out = (float*)d_out;
    char* ws   = (char*)d_ws;

    float*          partial = (float*)(ws + WSB_PART);
    unsigned short* Mt      = (unsigned short*)(ws + WSB_MT);
    float*          Tg      = (float*)(ws + WSB_T);
    float*          Cg      = (float*)(ws + WSB_C);
    float2*         murs    = (float2*)(ws + WSB_MURS);

    k_stats<<<dim3(128, 16), dim3(256), 0, stream>>>(x, partial, murs);

    k_combine<<<dim3(4, 16), dim3(256), 0, stream>>>(partial, ln_w, ln_b, Wl, bl,
                                                     Wr, br, Wo, bo, Mt, Tg, Cg);

    k_gemm5<<<dim3(64, 16), dim3(256), 0, stream>>>(x, murs, Mt, Tg, Cg, out);
}

// Round 9
// 143.832 us; speedup vs baseline: 2.4731x; 1.0781x over previous
//
#include <hip/hip_runtime.h>
#include <math.h>

#define B_  16
#define N_  8192
#define D_  128
#define H_  64
#define E_  64
#define EPSLN 1e-5f

typedef __attribute__((ext_vector_type(8))) short short8;
typedef __attribute__((ext_vector_type(4))) float f32x4;

// workspace layout (bytes):
//   colacc : B*D floats          @ 0        (8192 B)
//   Mt     : B*E*D bf16 (ushort) @ 8192     (262144 B)   Mt[b][e][d]
//   Tg     : B*E floats          @ 270336
//   Cg     : B*E floats          @ 274432
#define WSB_COL 0
#define WSB_MT  8192
#define WSB_T   270336
#define WSB_C   274432

static __device__ __forceinline__ unsigned short f2bf(float f) {
    union { float f; unsigned u; } c; c.f = f;
    unsigned u = c.u;
    return (unsigned short)((u + 0x7FFFu + ((u >> 16) & 1u)) >> 16);  // RNE
}

// ---------------------------------------------------------------------------
// Kernel A: colacc[b,d] = sum_i rsig_i * (x[b,i,d] - mu_i)
// Single global read: 64-row tile staged in LDS (pad +4 floats/row),
// stats via 4-lane groups, weighted colsum read column-wise from LDS.
// ---------------------------------------------------------------------------
__global__ __launch_bounds__(256) void k_stats(const float* __restrict__ x,
                                               float* __restrict__ colacc) {
    __shared__ float xs[64 * 132];           // 33.8 KB, row stride 132
    __shared__ float mul[64], rsl[64], red[128];
    int b = blockIdx.y, t = threadIdx.x;
    int rowbase = blockIdx.x * 64;
    size_t gbase = (size_t)(b * N_ + rowbase) * 32;  // in float4 units

    // stage: 2048 float4s, coalesced
    const float4* x4 = (const float4*)x;
#pragma unroll
    for (int k = 0; k < 8; ++k) {
        int idx = t + 256 * k;
        int row = idx >> 5, c4 = idx & 31;
        *(float4*)&xs[row * 132 + c4 * 4] = x4[gbase + idx];
    }
    __syncthreads();

    // stats: 4 threads per row
    {
        int r = t >> 2, q = t & 3;
        float s = 0.f, s2 = 0.f;
#pragma unroll
        for (int i = 0; i < 8; ++i) {
            float4 v = *(const float4*)&xs[r * 132 + q * 32 + i * 4];
            s  += (v.x + v.y) + (v.z + v.w);
            s2 += (v.x * v.x + v.y * v.y) + (v.z * v.z + v.w * v.w);
        }
        s  += __shfl_xor(s, 1, 64);  s  += __shfl_xor(s, 2, 64);
        s2 += __shfl_xor(s2, 1, 64); s2 += __shfl_xor(s2, 2, 64);
        if (q == 0) {
            float mu  = s * (1.f / D_);
            float var = s2 * (1.f / D_) - mu * mu;
            mul[r] = mu;
            rsl[r] = rsqrtf(var + EPSLN);
        }
    }
    __syncthreads();

    // weighted colsum: col c, half hh (rows hh*32..+31); 2-way banks = free
    int c = t & 127, hh = t >> 7;
    float acc = 0.f;
#pragma unroll 8
    for (int i = 0; i < 32; ++i) {
        int r = hh * 32 + i;
        acc += rsl[r] * (xs[r * 132 + c] - mul[r]);
    }
    if (hh == 1) red[c] = acc;
    __syncthreads();
    if (hh == 0) atomicAdd(&colacc[b * D_ + c], acc + red[c]);
}

// ---------------------------------------------------------------------------
// Kernel B: tiny per-batch combine; emits Mt (bf16, [e][d]), T, C.
//   cm[d]  = ln_w[d]*colacc[b,d]/N + ln_b[d]
//   ml[h]  = cm . Wl[:,h] + bl[h]
//   P[h,e] = ml[h]*Wo[h,e]
//   M[d,e] = ln_w[d] * sum_h Wr[d,h]*P[h,e]   -> stored transposed as bf16
//   T[e]   = colsum_d M[d,e];  C[e] = (ln_b.Wr + br) . P[:,e] + bo[e]
// ---------------------------------------------------------------------------
__global__ __launch_bounds__(256) void k_combine(const float* __restrict__ colacc,
                                                 const float* __restrict__ ln_w,
                                                 const float* __restrict__ ln_b,
                                                 const float* __restrict__ Wl,
                                                 const float* __restrict__ bl,
                                                 const float* __restrict__ Wr,
                                                 const float* __restrict__ br,
                                                 const float* __restrict__ Wo,
                                                 const float* __restrict__ bo,
                                                 unsigned short* __restrict__ Mt,
                                                 float* __restrict__ Tg,
                                                 float* __restrict__ Cg) {
    int b = blockIdx.y, dblk = blockIdx.x, t = threadIdx.x;
    __shared__ float cm[D_], ml[H_], uu[H_], qq[H_];
    __shared__ float P[H_ * E_];

    if (t < D_) cm[t] = ln_w[t] * colacc[b * D_ + t] * (1.f / N_) + ln_b[t];
    __syncthreads();

    if (t < H_) {
        float a = bl[t], u = 0.f, q = 0.f;
        for (int d = 0; d < D_; ++d) {
            float wr = Wr[d * H_ + t];
            a += cm[d] * Wl[d * H_ + t];
            u += ln_w[d] * wr;
            q += ln_b[d] * wr;
        }
        ml[t] = a; uu[t] = u; qq[t] = q + br[t];
    }
    __syncthreads();

#pragma unroll
    for (int k = 0; k < 16; ++k) {
        int idx = t + 256 * k;
        P[idx] = ml[idx >> 6] * Wo[idx];
    }
    __syncthreads();

    int d  = dblk * 32 + (t >> 3);
    int eo = (t & 7) * 8;
    float a0 = 0, a1 = 0, a2 = 0, a3 = 0, a4 = 0, a5 = 0, a6 = 0, a7 = 0;
    for (int h = 0; h < H_; ++h) {
        float wr = Wr[d * H_ + h];
        const float4* p4 = (const float4*)&P[h * E_ + eo];
        float4 pa = p4[0], pb = p4[1];
        a0 += wr * pa.x; a1 += wr * pa.y; a2 += wr * pa.z; a3 += wr * pa.w;
        a4 += wr * pb.x; a5 += wr * pb.y; a6 += wr * pb.z; a7 += wr * pb.w;
    }
    float wd = ln_w[d];
    size_t mb = (size_t)b * E_ * D_;
    Mt[mb + (size_t)(eo + 0) * D_ + d] = f2bf(wd * a0);
    Mt[mb + (size_t)(eo + 1) * D_ + d] = f2bf(wd * a1);
    Mt[mb + (size_t)(eo + 2) * D_ + d] = f2bf(wd * a2);
    Mt[mb + (size_t)(eo + 3) * D_ + d] = f2bf(wd * a3);
    Mt[mb + (size_t)(eo + 4) * D_ + d] = f2bf(wd * a4);
    Mt[mb + (size_t)(eo + 5) * D_ + d] = f2bf(wd * a5);
    Mt[mb + (size_t)(eo + 6) * D_ + d] = f2bf(wd * a6);
    Mt[mb + (size_t)(eo + 7) * D_ + d] = f2bf(wd * a7);

    if (dblk == 0 && t < E_) {
        float T = 0.f, C = bo[t];
        for (int h = 0; h < H_; ++h) {
            float p = P[h * E_ + t];
            T += uu[h] * p;
            C += qq[h] * p;
        }
        Tg[b * E_ + t] = T;
        Cg[b * E_ + t] = C;
    }
}

// ---------------------------------------------------------------------------
// Kernel C (MFMA bf16): out[b,j,e] = rsig_j*(x_j . M[:,e]) - rsig_j*mu_j*T[e] + C[e]
// 256-row tile. x staged to LDS as bf16 with XOR-swizzled 16B granules
// (granule g of row r stored at g ^ (r&15)): conflict-free b128 frag reads,
// rows 16B-aligned, no padding. M read as bf16 from global (L1-resident).
// One barrier; K fully unrolled (4 chunks of 32); per wave 4x4 16x16 tiles.
// LN stats computed inline during staging.
// ---------------------------------------------------------------------------
__global__ __launch_bounds__(256, 2) void k_gemm(const float* __restrict__ x,
                                                 const unsigned short* __restrict__ Mt,
                                                 const float* __restrict__ Tg,
                                                 const float* __restrict__ Cg,
                                                 float* __restrict__ out) {
    __shared__ short xs[256 * 128];  // 64 KB bf16
    __shared__ float mul[256], rsl[256], Tl[E_], Cl[E_];

    int b = blockIdx.y, t = threadIdx.x;
    int rowbase = blockIdx.x * 256;

    if (t < E_) { Tl[t] = Tg[b * E_ + t]; Cl[t] = Cg[b * E_ + t]; }

    // ---- stage row t: global fp32 -> bf16 LDS (swizzled), stats inline ----
    {
        const float4* xrow = (const float4*)(x + (size_t)(b * N_ + rowbase + t) * D_);
        float s = 0.f, s2 = 0.f;
        int sw = t & 15;
#pragma unroll
        for (int g = 0; g < 16; ++g) {          // 16B granule = 8 bf16
            float4 va = xrow[2 * g], vb = xrow[2 * g + 1];
            s  += (va.x + va.y) + (va.z + va.w) + (vb.x + vb.y) + (vb.z + vb.w);
            s2 += (va.x * va.x + va.y * va.y) + (va.z * va.z + va.w * va.w)
                + (vb.x * vb.x + vb.y * vb.y) + (vb.z * vb.z + vb.w * vb.w);
            short8 sv;
            sv[0] = (short)f2bf(va.x); sv[1] = (short)f2bf(va.y);
            sv[2] = (short)f2bf(va.z); sv[3] = (short)f2bf(va.w);
            sv[4] = (short)f2bf(vb.x); sv[5] = (short)f2bf(vb.y);
            sv[6] = (short)f2bf(vb.z); sv[7] = (short)f2bf(vb.w);
            *(short8*)&xs[t * 128 + ((g ^ sw) * 8)] = sv;
        }
        float mu  = s * (1.f / D_);
        float var = s2 * (1.f / D_) - mu * mu;
        mul[t] = mu;
        rsl[t] = rsqrtf(var + EPSLN);
    }
    __syncthreads();

    // ---- MFMA main: wave w -> rows w*64..+63 (4 m-tiles), cols 0..63 (4 n-tiles)
    int wv = t >> 6, lane = t & 63;
    int m16 = lane & 15, quad = lane >> 4;

    f32x4 acc[4][4];
#pragma unroll
    for (int i = 0; i < 4; ++i)
#pragma unroll
        for (int j = 0; j < 4; ++j) acc[i][j] = (f32x4){0.f, 0.f, 0.f, 0.f};

    const unsigned short* Mb = Mt + (size_t)b * E_ * D_;

#pragma unroll
    for (int kc = 0; kc < 4; ++kc) {
        short8 af[4], bf[4];
#pragma unroll
        for (int mt = 0; mt < 4; ++mt) {
            int row = wv * 64 + mt * 16 + m16;
            int g = kc * 4 + quad;
            af[mt] = *(const short8*)&xs[row * 128 + ((g ^ m16) * 8)];
        }
#pragma unroll
        for (int nt = 0; nt < 4; ++nt) {
            bf[nt] = *(const short8*)(Mb + (size_t)(nt * 16 + m16) * D_ + kc * 32 + quad * 8);
        }
#pragma unroll
        for (int mt = 0; mt < 4; ++mt)
#pragma unroll
            for (int nt = 0; nt < 4; ++nt)
                acc[mt][nt] = __builtin_amdgcn_mfma_f32_16x16x32_bf16(
                    af[mt], bf[nt], acc[mt][nt], 0, 0, 0);
    }

    // ---- epilogue: C/D layout col = lane&15, row = quad*4 + reg ----
    size_t outbase = (size_t)(b * N_ + rowbase) * E_;
#pragma unroll
    for (int mt = 0; mt < 4; ++mt) {
        int rb = wv * 64 + mt * 16 + quad * 4;
        float mu0 = mul[rb + 0], rs0 = rsl[rb + 0];
        float mu1 = mul[rb + 1], rs1 = rsl[rb + 1];
        float mu2 = mul[rb + 2], rs2 = rsl[rb + 2];
        float mu3 = mul[rb + 3], rs3 = rsl[rb + 3];
#pragma unroll
        for (int nt = 0; nt < 4; ++nt) {
            int col = nt * 16 + m16;
            float Tc = Tl[col], Cc = Cl[col];
            float* o = out + outbase + (size_t)rb * E_ + col;
            o[0 * E_] = rs0 * (acc[mt][nt][0] - mu0 * Tc) + Cc;
            o[1 * E_] = rs1 * (acc[mt][nt][1] - mu1 * Tc) + Cc;
            o[2 * E_] = rs2 * (acc[mt][nt][2] - mu2 * Tc) + Cc;
            o[3 * E_] = rs3 * (acc[mt][nt][3] - mu3 * Tc) + Cc;
        }
    }
}

extern "C" void kernel_launch(void* const* d_in, const int* in_sizes, int n_in,
                              void* d_out, int out_size, void* d_ws, size_t ws_size,
                              hipStream_t stream) {
    const float* x    = (const float*)d_in[0];
    const float* ln_w = (const float*)d_in[1];
    const float* ln_b = (const float*)d_in[2];
    const float* Wl   = (const float*)d_in[3];
    const float* bl   = (const float*)d_in[4];
    const float* Wr   = (const float*)d_in[5];
    const float* br   = (const float*)d_in[6];
    const float* Wo   = (const float*)d_in[7];
    const float* bo   = (const float*)d_in[8];
    float* out = (float*)d_out;
    char* ws   = (char*)d_ws;

    float*          colacc = (float*)(ws + WSB_COL);
    unsigned short* Mt     = (unsigned short*)(ws + WSB_MT);
    float*          Tg     = (float*)(ws + WSB_T);
    float*          Cg     = (float*)(ws + WSB_C);

    hipMemsetAsync(colacc, 0, B_ * D_ * sizeof(float), stream);

    k_stats<<<dim3(N_ / 64, B_), 256, 0, stream>>>(x, colacc);
    k_combine<<<dim3(4, B_), 256, 0, stream>>>(colacc, ln_w, ln_b, Wl, bl, Wr,
                                               br, Wo, bo, Mt, Tg, Cg);
    k_gemm<<<dim3(N_ / 256, B_), 256, 0, stream>>>(x, Mt, Tg, Cg, out);
}